// Round 10
// baseline (102.097 us; speedup 1.0000x reference)
//
#include <hip/hip_runtime.h>
#include <hip/hip_fp16.h>

#define TLEN 512
#define KLEN 11
#define XPAD 256          // left zero pad (covers pad <= 255 worst case)
#define XTOT 1024         // 16 KiB LDS: 1024 slots x 8 fp16 (8 batches interleaved)
#define NEGINF2 0xFC00FC00u

__device__ __forceinline__ unsigned pkmax_u(unsigned a, unsigned b) {
    unsigned d;
    asm("v_pk_max_f16 %0, %1, %2" : "=v"(d) : "v"(a), "v"(b));
    return d;
}
__device__ __forceinline__ unsigned pkadd_u(unsigned a, unsigned b) {
    unsigned d;
    asm("v_pk_add_f16 %0, %1, %2" : "=v"(d) : "v"(a), "v"(b));
    return d;
}
// acc += w2(SGPR) * h(VGPR) — VOP3P permits one SGPR source
__device__ __forceinline__ void pkfma_s(unsigned& acc, unsigned w2s, unsigned h) {
    asm("v_pk_fma_f16 %0, %1, %2, %0" : "+v"(acc) : "s"(w2s), "v"(h));
}

__device__ __forceinline__ unsigned wred_pkmax(unsigned x) {
    unsigned t;
    t = __builtin_amdgcn_update_dpp((int)NEGINF2, (int)x, 0x111, 0xF, 0xF, false);
    x = pkmax_u(x, t);
    t = __builtin_amdgcn_update_dpp((int)NEGINF2, (int)x, 0x112, 0xF, 0xF, false);
    x = pkmax_u(x, t);
    t = __builtin_amdgcn_update_dpp((int)NEGINF2, (int)x, 0x114, 0xF, 0xF, false);
    x = pkmax_u(x, t);
    t = __builtin_amdgcn_update_dpp((int)NEGINF2, (int)x, 0x118, 0xF, 0xF, false);
    x = pkmax_u(x, t);
    t = __builtin_amdgcn_update_dpp((int)NEGINF2, (int)x, 0x142, 0xA, 0xF, false);
    x = pkmax_u(x, t);
    t = __builtin_amdgcn_update_dpp((int)NEGINF2, (int)x, 0x143, 0xC, 0xF, false);
    x = pkmax_u(x, t);
    return (unsigned)__builtin_amdgcn_readlane((int)x, 63);
}
__device__ __forceinline__ unsigned wred_pkadd(unsigned x) {
    unsigned t;
    t = __builtin_amdgcn_update_dpp(0, (int)x, 0x111, 0xF, 0xF, false);
    x = pkadd_u(x, t);
    t = __builtin_amdgcn_update_dpp(0, (int)x, 0x112, 0xF, 0xF, false);
    x = pkadd_u(x, t);
    t = __builtin_amdgcn_update_dpp(0, (int)x, 0x114, 0xF, 0xF, false);
    x = pkadd_u(x, t);
    t = __builtin_amdgcn_update_dpp(0, (int)x, 0x118, 0xF, 0xF, false);
    x = pkadd_u(x, t);
    t = __builtin_amdgcn_update_dpp(0, (int)x, 0x142, 0xA, 0xF, false);
    x = pkadd_u(x, t);
    t = __builtin_amdgcn_update_dpp(0, (int)x, 0x143, 0xC, 0xF, false);
    x = pkadd_u(x, t);
    return (unsigned)__builtin_amdgcn_readlane((int)x, 63);
}

__device__ __forceinline__ __half2 as_h2(unsigned u) {
    __half2 h; __builtin_memcpy(&h, &u, 4); return h;
}
__device__ __forceinline__ unsigned as_u(__half2 h) {
    unsigned u; __builtin_memcpy(&u, &h, 4); return u;
}

// Fused, chunk-outer / taps-inner with per-tap hoisted slot offsets:
// per chunk, up to 11 INDEPENDENT ds_read_b128 (one waitcnt), 4 pk_fma each,
// then the chunk's epilogue immediately (only 4 acc regs live).
__global__ __launch_bounds__(256, 8) void rf_co(
    const float* __restrict__ x, const float* __restrict__ weight,
    const float* __restrict__ bias, const int* __restrict__ dilation,
    const int* __restrict__ padding, const int* __restrict__ out_len,
    float* __restrict__ out, int K)
{
    __shared__ uint4 xs[XTOT];
    const int t = threadIdx.x;

    // ---- fused staging: zero pads + 2 window slots per thread ----
    const uint4 z = make_uint4(0u, 0u, 0u, 0u);
    xs[t] = z;             // left pad  [0,256)
    xs[768 + t] = z;       // right pad [768,1024)
    const float* xg = x + (size_t)blockIdx.y * 8 * TLEN;
    #pragma unroll
    for (int h = 0; h < 2; ++h) {
        const int pos = t + h * 256;           // coalesced per q-row
        float v[8];
        #pragma unroll
        for (int q = 0; q < 8; ++q) v[q] = xg[q * TLEN + pos];
        uint4 s;
        s.x = as_u(__floats2half2_rn(v[0], v[1]));
        s.y = as_u(__floats2half2_rn(v[2], v[3]));
        s.z = as_u(__floats2half2_rn(v[4], v[5]));
        s.w = as_u(__floats2half2_rn(v[6], v[7]));
        xs[XPAD + pos] = s;
    }
    __syncthreads();

    const int lane = t & 63;
    const int ks = __builtin_amdgcn_readfirstlane(blockIdx.x * 4 + (t >> 6));

    const int dil  = dilation[ks];
    const int pd   = padding[ks];
    const int olen = out_len[ks];
    unsigned w2s[KLEN];
    bool wnz[KLEN];
    #pragma unroll
    for (int j = 0; j < KLEN; ++j) {
        const float wv = weight[ks * KLEN + j];            // scalar load
        wnz[j] = (wv != 0.0f);
        w2s[j] = __builtin_amdgcn_readfirstlane((int)as_u(__float2half2_rn(wv)));
    }
    const unsigned bias2 = __builtin_amdgcn_readfirstlane(
        (int)as_u(__float2half2_rn(bias[ks])));
    const __half2 zero2 = __float2half2_rn(0.0f);

    // per-tap slot offsets hoisted: inner reads need NO address math
    const int vbase = XPAD + lane - pd;
    int off[KLEN];
    #pragma unroll
    for (int j = 0; j < KLEN; ++j) off[j] = vbase + j * dil;

    unsigned mxu[4], cfu[4];
    #pragma unroll
    for (int q = 0; q < 4; ++q) { mxu[q] = NEGINF2; cfu[q] = 0u; }

    #pragma unroll
    for (int c = 0; c < 8; ++c) {
        const int p0 = c * 64;
        if (p0 < olen) {                                   // uniform: skip dead
            // 1) issue all live taps' reads (independent, imm-offset chunk)
            uint4 r[KLEN];
            #pragma unroll
            for (int j = 0; j < KLEN; ++j)
                if (wnz[j]) r[j] = xs[off[j] + p0];        // ds_read_b128
            // 2) accumulate (same tap order as R8 -> bit-identical)
            unsigned a0 = bias2, a1 = bias2, a2 = bias2, a3 = bias2;
            #pragma unroll
            for (int j = 0; j < KLEN; ++j) {
                if (wnz[j]) {
                    pkfma_s(a0, w2s[j], r[j].x);
                    pkfma_s(a1, w2s[j], r[j].y);
                    pkfma_s(a2, w2s[j], r[j].z);
                    pkfma_s(a3, w2s[j], r[j].w);
                }
            }
            // 3) immediate per-chunk epilogue
            if (p0 + 64 <= olen) {                         // fully valid
                mxu[0] = pkmax_u(mxu[0], a0);
                mxu[1] = pkmax_u(mxu[1], a1);
                mxu[2] = pkmax_u(mxu[2], a2);
                mxu[3] = pkmax_u(mxu[3], a3);
                cfu[0] = pkadd_u(cfu[0], as_u(__hgt2(as_h2(a0), zero2)));
                cfu[1] = pkadd_u(cfu[1], as_u(__hgt2(as_h2(a1), zero2)));
                cfu[2] = pkadd_u(cfu[2], as_u(__hgt2(as_h2(a2), zero2)));
                cfu[3] = pkadd_u(cfu[3], as_u(__hgt2(as_h2(a3), zero2)));
            } else {                                       // boundary
                const bool vld = lane < (olen - p0);
                mxu[0] = pkmax_u(mxu[0], vld ? a0 : NEGINF2);
                mxu[1] = pkmax_u(mxu[1], vld ? a1 : NEGINF2);
                mxu[2] = pkmax_u(mxu[2], vld ? a2 : NEGINF2);
                mxu[3] = pkmax_u(mxu[3], vld ? a3 : NEGINF2);
                cfu[0] = pkadd_u(cfu[0], vld ? as_u(__hgt2(as_h2(a0), zero2)) : 0u);
                cfu[1] = pkadd_u(cfu[1], vld ? as_u(__hgt2(as_h2(a1), zero2)) : 0u);
                cfu[2] = pkadd_u(cfu[2], vld ? as_u(__hgt2(as_h2(a2), zero2)) : 0u);
                cfu[3] = pkadd_u(cfu[3], vld ? as_u(__hgt2(as_h2(a3), zero2)) : 0u);
            }
        }
    }

    #pragma unroll
    for (int q = 0; q < 4; ++q) {
        mxu[q] = wred_pkmax(mxu[q]);
        cfu[q] = wred_pkadd(cfu[q]);
    }

    if (lane == 0) {
        const float inv = 1.0f / (float)olen;
        const size_t row = (size_t)2 * K;
        float* o = out + (size_t)blockIdx.y * 8 * row + 2 * ks;
        #pragma unroll
        for (int q = 0; q < 4; ++q) {
            const __half2 m = as_h2(mxu[q]);
            const __half2 c = as_h2(cfu[q]);
            *(float2*)(o + (2 * q) * row)     = make_float2(__low2float(m),  __low2float(c) * inv);
            *(float2*)(o + (2 * q + 1) * row) = make_float2(__high2float(m), __high2float(c) * inv);
        }
    }
}

extern "C" void kernel_launch(void* const* d_in, const int* in_sizes, int n_in,
                              void* d_out, int out_size, void* d_ws, size_t ws_size,
                              hipStream_t stream) {
    const float* x    = (const float*)d_in[0];
    const float* w    = (const float*)d_in[1];
    const float* bias = (const float*)d_in[2];
    const int* dil    = (const int*)d_in[3];
    const int* pad    = (const int*)d_in[4];
    const int* olen   = (const int*)d_in[5];
    float* out        = (float*)d_out;

    const int K = in_sizes[2];          // 4096
    const int B = in_sizes[0] / TLEN;   // 32

    dim3 grid(K / 4, B / 8);            // 1024 x 4 blocks, 4 waves each
    rf_co<<<grid, 256, 0, stream>>>(x, w, bias, dil, pad, olen, out, K);
    (void)n_in; (void)out_size; (void)d_ws; (void)ws_size;
}

// Round 11
// 91.010 us; speedup vs baseline: 1.1218x; 1.1218x over previous
//
#include <hip/hip_runtime.h>
#include <hip/hip_fp16.h>

#define TLEN 512
#define KLEN 11
#define XPAD 256          // covers slot >= 1 for pad <= 255
#define XTOT 1024         // 16 KiB LDS: 1024 slots x 8 fp16 (8 batches interleaved)
#define NEGINF2 0xFC00FC00u

__device__ __forceinline__ unsigned pkmax_u(unsigned a, unsigned b) {
    unsigned d;
    asm("v_pk_max_f16 %0, %1, %2" : "=v"(d) : "v"(a), "v"(b));
    return d;
}
__device__ __forceinline__ unsigned pkadd_u(unsigned a, unsigned b) {
    unsigned d;
    asm("v_pk_add_f16 %0, %1, %2" : "=v"(d) : "v"(a), "v"(b));
    return d;
}

__device__ __forceinline__ unsigned wred_pkmax(unsigned x) {
    unsigned t;
    t = __builtin_amdgcn_update_dpp((int)NEGINF2, (int)x, 0x111, 0xF, 0xF, false);
    x = pkmax_u(x, t);
    t = __builtin_amdgcn_update_dpp((int)NEGINF2, (int)x, 0x112, 0xF, 0xF, false);
    x = pkmax_u(x, t);
    t = __builtin_amdgcn_update_dpp((int)NEGINF2, (int)x, 0x114, 0xF, 0xF, false);
    x = pkmax_u(x, t);
    t = __builtin_amdgcn_update_dpp((int)NEGINF2, (int)x, 0x118, 0xF, 0xF, false);
    x = pkmax_u(x, t);
    t = __builtin_amdgcn_update_dpp((int)NEGINF2, (int)x, 0x142, 0xA, 0xF, false);
    x = pkmax_u(x, t);
    t = __builtin_amdgcn_update_dpp((int)NEGINF2, (int)x, 0x143, 0xC, 0xF, false);
    x = pkmax_u(x, t);
    return (unsigned)__builtin_amdgcn_readlane((int)x, 63);
}
__device__ __forceinline__ unsigned wred_pkadd(unsigned x) {
    unsigned t;
    t = __builtin_amdgcn_update_dpp(0, (int)x, 0x111, 0xF, 0xF, false);
    x = pkadd_u(x, t);
    t = __builtin_amdgcn_update_dpp(0, (int)x, 0x112, 0xF, 0xF, false);
    x = pkadd_u(x, t);
    t = __builtin_amdgcn_update_dpp(0, (int)x, 0x114, 0xF, 0xF, false);
    x = pkadd_u(x, t);
    t = __builtin_amdgcn_update_dpp(0, (int)x, 0x118, 0xF, 0xF, false);
    x = pkadd_u(x, t);
    t = __builtin_amdgcn_update_dpp(0, (int)x, 0x142, 0xA, 0xF, false);
    x = pkadd_u(x, t);
    t = __builtin_amdgcn_update_dpp(0, (int)x, 0x143, 0xC, 0xF, false);
    x = pkadd_u(x, t);
    return (unsigned)__builtin_amdgcn_readlane((int)x, 63);
}

__device__ __forceinline__ __half2 as_h2(unsigned u) {
    __half2 h; __builtin_memcpy(&h, &u, 4); return h;
}
__device__ __forceinline__ unsigned as_u(__half2 h) {
    unsigned u; __builtin_memcpy(&u, &h, 4); return u;
}

// Pre-kernel: zero-padded, 8-batch-interleaved fp16 windows in ws.
__global__ __launch_bounds__(256) void stage_ws_h(const float* __restrict__ x,
                                                  uint4* __restrict__ ws) {
    const int t = threadIdx.x;
    const int g = blockIdx.x >> 2;
    const int seg = blockIdx.x & 3;
    const int slot = seg * 256 + t;
    uint4 v = make_uint4(0u, 0u, 0u, 0u);
    if (slot >= XPAD && slot < XPAD + TLEN) {
        const int pos = slot - XPAD;
        const float* xg = x + (size_t)g * 8 * TLEN;
        unsigned h[8];
        #pragma unroll
        for (int q = 0; q < 8; ++q)
            h[q] = (unsigned)__half_as_ushort(__float2half(xg[q * TLEN + pos]));
        v.x = h[0] | (h[1] << 16);
        v.y = h[2] | (h[3] << 16);
        v.z = h[4] | (h[5] << 16);
        v.w = h[6] | (h[7] << 16);
    }
    ws[(size_t)g * XTOT + slot] = v;
}

// taps-outer / chunks-inner: per tap ONE address, 8 independent ds_read_b128
// at immediate offsets; persistent per-chunk half2 accumulators.
// Best-measured configuration of the session (bench 89.08 us, absmax 0.125).
__global__ __launch_bounds__(256, 4) void rf_kernel_h3(
    const uint4* __restrict__ ws, const float* __restrict__ weight,
    const float* __restrict__ bias, const int* __restrict__ dilation,
    const int* __restrict__ padding, const int* __restrict__ out_len,
    float* __restrict__ out, int K)
{
    __shared__ uint4 xs[XTOT];
    const int t = threadIdx.x;
    const uint4* wsg = ws + (size_t)blockIdx.y * XTOT;

    xs[t]       = wsg[t];
    xs[t + 256] = wsg[t + 256];
    xs[t + 512] = wsg[t + 512];
    xs[t + 768] = wsg[t + 768];
    __syncthreads();

    const int lane = t & 63;
    const int ks = __builtin_amdgcn_readfirstlane(blockIdx.x * 4 + (t >> 6));

    const int dil  = dilation[ks];
    const int pd   = padding[ks];
    const int olen = out_len[ks];
    float wjf[KLEN];
    __half2 w2[KLEN];
    #pragma unroll
    for (int j = 0; j < KLEN; ++j) {
        wjf[j] = weight[ks * KLEN + j];
        w2[j] = __float2half2_rn(wjf[j]);
    }
    const __half2 bias2 = __float2half2_rn(bias[ks]);
    const __half2 zero2 = __float2half2_rn(0.0f);

    const int vbase = XPAD + lane - pd;

    __half2 acc[8][4];
    #pragma unroll
    for (int c = 0; c < 8; ++c)
        #pragma unroll
        for (int q = 0; q < 4; ++q) acc[c][q] = bias2;

    #pragma unroll
    for (int j = 0; j < KLEN; ++j) {
        if (wjf[j] != 0.0f) {                          // uniform: skip zero taps
            const uint4* xp = xs + (vbase + j * dil);  // one addr per tap
            #pragma unroll
            for (int c = 0; c < 8; ++c) {
                if (c * 64 < olen) {                   // uniform: skip dead chunks
                    const uint4 r = xp[c * 64];        // ds_read_b128, imm c*1024
                    acc[c][0] = __hfma2(w2[j], as_h2(r.x), acc[c][0]);
                    acc[c][1] = __hfma2(w2[j], as_h2(r.y), acc[c][1]);
                    acc[c][2] = __hfma2(w2[j], as_h2(r.z), acc[c][2]);
                    acc[c][3] = __hfma2(w2[j], as_h2(r.w), acc[c][3]);
                }
            }
        }
    }

    unsigned mxu[4], cfu[4];
    #pragma unroll
    for (int q = 0; q < 4; ++q) { mxu[q] = NEGINF2; cfu[q] = 0u; }

    #pragma unroll
    for (int c = 0; c < 8; ++c) {
        const int p0 = c * 64;
        if (p0 + 64 <= olen) {                         // fully-valid chunk
            #pragma unroll
            for (int q = 0; q < 4; ++q) {
                mxu[q] = pkmax_u(mxu[q], as_u(acc[c][q]));
                cfu[q] = pkadd_u(cfu[q], as_u(__hgt2(acc[c][q], zero2)));
            }
        } else if (p0 < olen) {                        // boundary chunk
            const bool vld = lane < (olen - p0);
            #pragma unroll
            for (int q = 0; q < 4; ++q) {
                const unsigned a = vld ? as_u(acc[c][q]) : NEGINF2;
                mxu[q] = pkmax_u(mxu[q], a);
                const unsigned g = vld ? as_u(__hgt2(acc[c][q], zero2)) : 0u;
                cfu[q] = pkadd_u(cfu[q], g);
            }
        }
    }

    #pragma unroll
    for (int q = 0; q < 4; ++q) {
        mxu[q] = wred_pkmax(mxu[q]);
        cfu[q] = wred_pkadd(cfu[q]);
    }

    if (lane == 0) {
        const float inv = 1.0f / (float)olen;
        const size_t row = (size_t)2 * K;
        float* o = out + (size_t)blockIdx.y * 8 * row + 2 * ks;
        #pragma unroll
        for (int q = 0; q < 4; ++q) {
            const __half2 m = as_h2(mxu[q]);
            const __half2 c = as_h2(cfu[q]);
            *(float2*)(o + (2 * q) * row)     = make_float2(__low2float(m),  __low2float(c) * inv);
            *(float2*)(o + (2 * q + 1) * row) = make_float2(__high2float(m), __high2float(c) * inv);
        }
    }
}

extern "C" void kernel_launch(void* const* d_in, const int* in_sizes, int n_in,
                              void* d_out, int out_size, void* d_ws, size_t ws_size,
                              hipStream_t stream) {
    const float* x    = (const float*)d_in[0];
    const float* w    = (const float*)d_in[1];
    const float* bias = (const float*)d_in[2];
    const int* dil    = (const int*)d_in[3];
    const int* pad    = (const int*)d_in[4];
    const int* olen   = (const int*)d_in[5];
    float* out        = (float*)d_out;

    const int K = in_sizes[2];          // 4096
    const int B = in_sizes[0] / TLEN;   // 32
    const int G = B / 8;                // 4 batch groups

    uint4* ws = (uint4*)d_ws;
    stage_ws_h<<<dim3(G * 4), 256, 0, stream>>>(x, ws);
    dim3 grid(K / 4, G);                // 1024 x 4 blocks, 4 waves each
    rf_kernel_h3<<<grid, 256, 0, stream>>>(ws, w, bias, dil, pad, olen, out, K);
    (void)n_in; (void)out_size; (void)ws_size;
}